// Round 4
// baseline (281.180 us; speedup 1.0000x reference)
//
#include <hip/hip_runtime.h>
#include <hip/hip_cooperative_groups.h>
#include <math.h>

namespace cg = cooperative_groups;

// Problem constants: B=32, T=2048, H=512, D=2H=1024
constexpr int B = 32;
constexpr int T = 2048;
constexpr int H = 512;
constexpr int D = 2 * H;          // 1024
constexpr int CPB  = 32;          // chunks per batch (phases A and B)
constexpr int ROWS = T / CPB;     // 64 rows per work item
constexpr int NWA  = B * CPB;     // 1024 phase-A work items
constexpr int NWB  = B * CPB;     // 1024 phase-B work items (one partial each)
constexpr int RCB  = 8;           // r-combine work items per batch
constexpr int PPC  = CPB / RCB;   // 4 partials per combine work item
constexpr int ACB  = 4;           // alpha work items per batch

// ---------------------------------------------------------------------------
// Cooperative mega-kernel. Grid-stride work decomposition so any grid size
// that the occupancy query returns is correct.
//  A: hpart[wb][d] = sum over 64 rows of h*mask      (no atomics, no zeroing)
//     + zero r
//  sync
//  B: per block: hsum = sum of 32 hpart rows (L2); online-softmax pass over
//     lstm (16 rows/wave); 4-wave LDS merge -> one partial (m,s,racc[D])
//     per work item; write beta.
//  sync
//  C: r = weighted combine of 32 partials (atomicAdd, r pre-zeroed);
//     alpha = exp(beta - M) * invS.
// ---------------------------------------------------------------------------
__global__ __launch_bounds__(256, 4)
void k_mega(const float* __restrict__ h,
            const float* __restrict__ lstm,
            const float* __restrict__ mask,
            float* __restrict__ r,
            float* __restrict__ alpha,
            float* __restrict__ hpart,   // [NWA][D]
            float* __restrict__ pm,      // [NWB]
            float* __restrict__ ps,      // [NWB]
            float* __restrict__ beta,    // [B][T]
            float* __restrict__ prb) {   // [NWB][D]
    cg::grid_group grid = cg::this_grid();
    const int tid = threadIdx.x;
    const int nb  = gridDim.x;

    // ---------------- Phase A ----------------
    for (int wb = blockIdx.x; wb < NWA; wb += nb) {
        const int b  = wb >> 5;
        const int c  = wb & 31;
        const int t0 = c * ROWS;
        const float4* hp = (const float4*)(h + ((size_t)b * T + t0) * D) + tid;
        const float4* mp = (const float4*)(mask + ((size_t)b * T + t0) * H) + (tid & 127);
        float4 acc = make_float4(0.f, 0.f, 0.f, 0.f);
        for (int t = 0; t < ROWS; ++t) {
            float4 hv = hp[t * (D / 4)];
            float4 mv = mp[t * (H / 4)];
            acc.x += hv.x * mv.x;
            acc.y += hv.y * mv.y;
            acc.z += hv.z * mv.z;
            acc.w += hv.w * mv.w;
        }
        ((float4*)(hpart + (size_t)wb * D))[tid] = acc;
    }
    // zero r: B*D = 32K floats = 32 work items x 256 threads x float4
    for (int wb = blockIdx.x; wb < (B * D) / 1024; wb += nb)
        ((float4*)r)[wb * 256 + tid] = make_float4(0.f, 0.f, 0.f, 0.f);

    grid.sync();

    // ---------------- Phase B ----------------
    __shared__ alignas(16) float lracc[4][D];   // 16 KB
    __shared__ float lms[8];                    // m[4], s[4]
    const int w    = tid >> 6;
    const int lane = tid & 63;

    for (int wb = blockIdx.x; wb < NWB; wb += nb) {
        const int b  = wb >> 5;
        const int ch = wb & 31;

        // reconstruct hsum fragment for this lane's 16 columns
        float4 hv[4] = {make_float4(0,0,0,0), make_float4(0,0,0,0),
                        make_float4(0,0,0,0), make_float4(0,0,0,0)};
        for (int p = 0; p < CPB; ++p) {
            const float4* pp = (const float4*)(hpart + (size_t)(b * CPB + p) * D);
#pragma unroll
            for (int k = 0; k < 4; ++k) {
                float4 v = pp[lane + 64 * k];
                hv[k].x += v.x; hv[k].y += v.y; hv[k].z += v.z; hv[k].w += v.w;
            }
        }

        float m = -INFINITY, s = 0.f;
        float4 racc[4] = {make_float4(0,0,0,0), make_float4(0,0,0,0),
                          make_float4(0,0,0,0), make_float4(0,0,0,0)};
        const int t0 = ch * ROWS;
        for (int i = 0; i < ROWS / 4; ++i) {
            const int t = t0 + i * 4 + w;
            const float4* lp = (const float4*)(lstm + ((size_t)b * T + t) * D);
            float4 lv[4];
#pragma unroll
            for (int k = 0; k < 4; ++k) lv[k] = lp[lane + 64 * k];

            float acc = 0.f;
#pragma unroll
            for (int k = 0; k < 4; ++k)
                acc += lv[k].x * hv[k].x + lv[k].y * hv[k].y +
                       lv[k].z * hv[k].z + lv[k].w * hv[k].w;
#pragma unroll
            for (int o = 32; o >= 1; o >>= 1) acc += __shfl_xor(acc, o, 64);
            if (lane == 0) beta[b * T + t] = acc;

            if (acc <= m) {
                const float e = expf(acc - m);
                s += e;
#pragma unroll
                for (int k = 0; k < 4; ++k) {
                    racc[k].x = fmaf(e, lv[k].x, racc[k].x);
                    racc[k].y = fmaf(e, lv[k].y, racc[k].y);
                    racc[k].z = fmaf(e, lv[k].z, racc[k].z);
                    racc[k].w = fmaf(e, lv[k].w, racc[k].w);
                }
            } else {
                const float c2 = expf(m - acc);   // expf(-inf)=0 first row
                s = fmaf(s, c2, 1.f);
#pragma unroll
                for (int k = 0; k < 4; ++k) {
                    racc[k].x = fmaf(racc[k].x, c2, lv[k].x);
                    racc[k].y = fmaf(racc[k].y, c2, lv[k].y);
                    racc[k].z = fmaf(racc[k].z, c2, lv[k].z);
                    racc[k].w = fmaf(racc[k].w, c2, lv[k].w);
                }
                m = acc;
            }
        }

        // 4-wave merge via LDS -> one partial per work item
#pragma unroll
        for (int k = 0; k < 4; ++k)
            *(float4*)&lracc[w][(lane + 64 * k) * 4] = racc[k];
        if (lane == 0) { lms[w] = m; lms[4 + w] = s; }
        __syncthreads();

        const float mB = fmaxf(fmaxf(lms[0], lms[1]), fmaxf(lms[2], lms[3]));
        const float w0 = expf(lms[0] - mB), w1 = expf(lms[1] - mB);
        const float w2 = expf(lms[2] - mB), w3 = expf(lms[3] - mB);
        const float sB = lms[4] * w0 + lms[5] * w1 + lms[6] * w2 + lms[7] * w3;
        if (tid == 0) { pm[wb] = mB; ps[wb] = sB; }

        const int col = tid * 4;
        const float4 a0 = *(const float4*)&lracc[0][col];
        const float4 a1 = *(const float4*)&lracc[1][col];
        const float4 a2 = *(const float4*)&lracc[2][col];
        const float4 a3 = *(const float4*)&lracc[3][col];
        float4 rb;
        rb.x = a0.x * w0 + a1.x * w1 + a2.x * w2 + a3.x * w3;
        rb.y = a0.y * w0 + a1.y * w1 + a2.y * w2 + a3.y * w3;
        rb.z = a0.z * w0 + a1.z * w1 + a2.z * w2 + a3.z * w3;
        rb.w = a0.w * w0 + a1.w * w1 + a2.w * w2 + a3.w * w3;
        ((float4*)(prb + (size_t)wb * D))[tid] = rb;
        __syncthreads();   // protect LDS before next stride iteration
    }

    grid.sync();

    // ---------------- Phase C: r combine ----------------
    for (int wb = blockIdx.x; wb < B * RCB; wb += nb) {
        const int b  = wb >> 3;
        const int ck = wb & 7;
        float M = -INFINITY;
        for (int p = 0; p < CPB; ++p) M = fmaxf(M, pm[b * CPB + p]);
        float S = 0.f;
        for (int p = 0; p < CPB; ++p) S += expf(pm[b * CPB + p] - M) * ps[b * CPB + p];
        const float invS = 1.f / S;

        float4 acc = make_float4(0.f, 0.f, 0.f, 0.f);
        for (int p = ck * PPC; p < ck * PPC + PPC; ++p) {
            const float wp = expf(pm[b * CPB + p] - M) * invS;
            const float4 v = ((const float4*)(prb + (size_t)(b * CPB + p) * D))[tid];
            acc.x = fmaf(wp, v.x, acc.x);
            acc.y = fmaf(wp, v.y, acc.y);
            acc.z = fmaf(wp, v.z, acc.z);
            acc.w = fmaf(wp, v.w, acc.w);
        }
        float* dst = r + (size_t)b * D + tid * 4;
        atomicAdd(dst + 0, acc.x);
        atomicAdd(dst + 1, acc.y);
        atomicAdd(dst + 2, acc.z);
        atomicAdd(dst + 3, acc.w);
    }
    // ---------------- Phase C: alpha ----------------
    for (int wb = blockIdx.x; wb < B * ACB; wb += nb) {
        const int b = wb >> 2;
        const int q = wb & 3;
        float M = -INFINITY;
        for (int p = 0; p < CPB; ++p) M = fmaxf(M, pm[b * CPB + p]);
        float S = 0.f;
        for (int p = 0; p < CPB; ++p) S += expf(pm[b * CPB + p] - M) * ps[b * CPB + p];
        const float invS = 1.f / S;
#pragma unroll
        for (int k2 = 0; k2 < 2; ++k2) {
            const int t = q * 512 + k2 * 256 + tid;
            alpha[b * T + t] = expf(beta[b * T + t] - M) * invS;
        }
    }
}

// ===========================================================================
// Fallback path (non-cooperative, R2 structure) in case cooperative launch
// is rejected by graph capture.
// ===========================================================================
__global__ void f_zero(float* __restrict__ p) {
    ((float4*)p)[blockIdx.x * 256 + threadIdx.x] = make_float4(0.f, 0.f, 0.f, 0.f);
}

__global__ void f_hsum(const float* __restrict__ h, const float* __restrict__ mask,
                       float* __restrict__ hsum) {
    const int b = blockIdx.x / CPB, ts = blockIdx.x % CPB, tid = threadIdx.x;
    const int t0 = ts * ROWS;
    const float4* hp = (const float4*)(h + ((size_t)b * T + t0) * D) + tid;
    const float4* mp = (const float4*)(mask + ((size_t)b * T + t0) * H) + (tid & 127);
    float4 acc = make_float4(0.f, 0.f, 0.f, 0.f);
    for (int t = 0; t < ROWS; ++t) {
        float4 hv = hp[t * (D / 4)];
        float4 mv = mp[t * (H / 4)];
        acc.x += hv.x * mv.x; acc.y += hv.y * mv.y;
        acc.z += hv.z * mv.z; acc.w += hv.w * mv.w;
    }
    float* dst = hsum + b * D + tid * 4;
    atomicAdd(dst + 0, acc.x); atomicAdd(dst + 1, acc.y);
    atomicAdd(dst + 2, acc.z); atomicAdd(dst + 3, acc.w);
}

__global__ void f_fused(const float* __restrict__ lstm, const float* __restrict__ hsum,
                        float* __restrict__ beta, float* __restrict__ pm,
                        float* __restrict__ ps, float* __restrict__ pr) {
    const int b = blockIdx.x / CPB, ch = blockIdx.x % CPB;
    const int w = threadIdx.x >> 6, lane = threadIdx.x & 63;
    const int pidx = ch * 4 + w;
    const float4* hp = (const float4*)(hsum + (size_t)b * D);
    float4 hv[4];
#pragma unroll
    for (int k = 0; k < 4; ++k) hv[k] = hp[lane + 64 * k];
    float m = -INFINITY, s = 0.f;
    float4 racc[4] = {make_float4(0,0,0,0), make_float4(0,0,0,0),
                      make_float4(0,0,0,0), make_float4(0,0,0,0)};
    const int t0 = ch * ROWS;
    for (int i = 0; i < ROWS / 4; ++i) {
        const int t = t0 + i * 4 + w;
        const float4* lp = (const float4*)(lstm + ((size_t)b * T + t) * D);
        float4 lv[4];
#pragma unroll
        for (int k = 0; k < 4; ++k) lv[k] = lp[lane + 64 * k];
        float acc = 0.f;
#pragma unroll
        for (int k = 0; k < 4; ++k)
            acc += lv[k].x * hv[k].x + lv[k].y * hv[k].y +
                   lv[k].z * hv[k].z + lv[k].w * hv[k].w;
#pragma unroll
        for (int o = 32; o >= 1; o >>= 1) acc += __shfl_xor(acc, o, 64);
        if (lane == 0) beta[b * T + t] = acc;
        if (acc <= m) {
            const float e = expf(acc - m);
            s += e;
#pragma unroll
            for (int k = 0; k < 4; ++k) {
                racc[k].x = fmaf(e, lv[k].x, racc[k].x);
                racc[k].y = fmaf(e, lv[k].y, racc[k].y);
                racc[k].z = fmaf(e, lv[k].z, racc[k].z);
                racc[k].w = fmaf(e, lv[k].w, racc[k].w);
            }
        } else {
            const float c2 = expf(m - acc);
            s = fmaf(s, c2, 1.f);
#pragma unroll
            for (int k = 0; k < 4; ++k) {
                racc[k].x = fmaf(racc[k].x, c2, lv[k].x);
                racc[k].y = fmaf(racc[k].y, c2, lv[k].y);
                racc[k].z = fmaf(racc[k].z, c2, lv[k].z);
                racc[k].w = fmaf(racc[k].w, c2, lv[k].w);
            }
            m = acc;
        }
    }
    const int NP = CPB * 4;
    if (lane == 0) { pm[b * NP + pidx] = m; ps[b * NP + pidx] = s; }
    float4* prp = (float4*)(pr + ((size_t)(b * NP + pidx)) * D);
#pragma unroll
    for (int k = 0; k < 4; ++k) prp[lane + 64 * k] = racc[k];
}

__global__ void f_combine(const float* __restrict__ pm, const float* __restrict__ ps,
                          const float* __restrict__ pr, const float* __restrict__ beta,
                          float* __restrict__ r, float* __restrict__ alpha) {
    const int NP = CPB * 4;
    const int b = blockIdx.x, tid = threadIdx.x;
    __shared__ float wsm[CPB * 4];
    float M = -INFINITY;
    for (int p = 0; p < NP; ++p) M = fmaxf(M, pm[b * NP + p]);
    if (tid < NP) wsm[tid] = expf(pm[b * NP + tid] - M);
    __syncthreads();
    float S = 0.f;
    for (int p = 0; p < NP; ++p) S += wsm[p] * ps[b * NP + p];
    const float invS = 1.f / S;
    float4 acc = make_float4(0.f, 0.f, 0.f, 0.f);
    for (int p = 0; p < NP; ++p) {
        const float wp = wsm[p];
        const float4 v = ((const float4*)(pr + ((size_t)(b * NP + p)) * D))[tid];
        acc.x = fmaf(wp, v.x, acc.x); acc.y = fmaf(wp, v.y, acc.y);
        acc.z = fmaf(wp, v.z, acc.z); acc.w = fmaf(wp, v.w, acc.w);
    }
    acc.x *= invS; acc.y *= invS; acc.z *= invS; acc.w *= invS;
    ((float4*)(r + (size_t)b * D))[tid] = acc;
#pragma unroll
    for (int i = 0; i < 8; ++i) {
        const int t = tid + i * 256;
        alpha[b * T + t] = expf(beta[b * T + t] - M) * invS;
    }
}

// ===========================================================================
extern "C" void kernel_launch(void* const* d_in, const int* in_sizes, int n_in,
                              void* d_out, int out_size, void* d_ws, size_t ws_size,
                              hipStream_t stream) {
    const float* h    = (const float*)d_in[0];   // [B,T,D]
    const float* lstm = (const float*)d_in[1];   // [B,T,D]
    const float* mask = (const float*)d_in[2];   // [B,T,H]

    float* out   = (float*)d_out;
    float* r     = out;            // [B,1,D]
    float* alpha = out + B * D;    // [B,T]

    float* hpart = (float*)d_ws;                   // NWA*D   = 4 MB
    float* pm    = hpart + (size_t)NWA * D;        // NWB
    float* ps    = pm + NWB;                       // NWB
    float* beta  = ps + NWB;                       // B*T
    float* prb   = beta + (size_t)B * T;           // NWB*D   = 4 MB

    int blocksPerCU = 0;
    hipError_t qe = hipOccupancyMaxActiveBlocksPerMultiprocessor(
        &blocksPerCU, k_mega, 256, 0);
    if (qe != hipSuccess || blocksPerCU < 1) blocksPerCU = 2;
    int nblk = blocksPerCU * 256;                  // 256 CUs on MI355X
    if (nblk > NWA) nblk = NWA;

    void* kargs[] = {(void*)&h, (void*)&lstm, (void*)&mask, (void*)&r,
                     (void*)&alpha, (void*)&hpart, (void*)&pm, (void*)&ps,
                     (void*)&beta, (void*)&prb};
    hipError_t le = hipLaunchCooperativeKernel(
        k_mega, dim3(nblk), dim3(256), kargs, 0, stream);

    if (le != hipSuccess) {
        // Fallback: non-cooperative 4-kernel path (R2 structure).
        // Reuse ws: hsum in hpart's space; pm/ps sized NP=128 per batch fits
        // in the 4 MB prb region's headroom: lay out separately.
        float* hsum = hpart;                        // B*D floats
        float* fpm  = hpart + B * D;                // B*128
        float* fps  = fpm + B * 128;                // B*128
        float* fbeta= fps + B * 128;                // B*T
        float* fpr  = fbeta + (size_t)B * T;        // B*128*D = 16 MB
        f_zero   <<<B * D / 1024, 256, 0, stream>>>(hsum);
        f_hsum   <<<B * CPB,      256, 0, stream>>>(h, mask, hsum);
        f_fused  <<<B * CPB,      256, 0, stream>>>(lstm, hsum, fbeta, fpm, fps, fpr);
        f_combine<<<B,            256, 0, stream>>>(fpm, fps, fpr, fbeta, r, alpha);
    }
}

// Round 5
// 133.851 us; speedup vs baseline: 2.1007x; 2.1007x over previous
//
#include <hip/hip_runtime.h>
#include <math.h>

// Problem constants: B=32, T=2048, H=512, D=2H=1024
constexpr int B = 32;
constexpr int T = 2048;
constexpr int H = 512;
constexpr int D = 2 * H;            // 1024
constexpr int CPH  = 16;            // hsum chunks per batch
constexpr int RWH  = T / CPH;       // 128 rows per hpart block
constexpr int CPF  = 32;            // fused chunks per batch
constexpr int RWF  = T / CPF;       // 64 rows per fused block
constexpr int ACB  = 4;             // alpha blocks per batch

// ---------------------------------------------------------------------------
// Kernel 1: hpart[b,c,d] = sum over 128 rows of h*mask2.  No atomics.
// grid = B*CPH = 512 blocks, 256 threads, thread owns float4 col tid.
// ---------------------------------------------------------------------------
__global__ void k_hpart(const float* __restrict__ h,
                        const float* __restrict__ mask,
                        float* __restrict__ hpart) {
    const int b   = blockIdx.x / CPH;
    const int c   = blockIdx.x % CPH;
    const int tid = threadIdx.x;
    const int t0  = c * RWH;

    const float4* hp = (const float4*)(h + ((size_t)b * T + t0) * D) + tid;
    const float4* mp = (const float4*)(mask + ((size_t)b * T + t0) * H) + (tid & 127);

    float4 acc = make_float4(0.f, 0.f, 0.f, 0.f);
    for (int t = 0; t < RWH; ++t) {
        float4 hv = hp[t * (D / 4)];
        float4 mv = mp[t * (H / 4)];
        acc.x += hv.x * mv.x;
        acc.y += hv.y * mv.y;
        acc.z += hv.z * mv.z;
        acc.w += hv.w * mv.w;
    }
    ((float4*)(hpart + (size_t)blockIdx.x * D))[tid] = acc;
}

// ---------------------------------------------------------------------------
// Kernel 2 (fused): reconstruct hsum from hpart (L3-hit), single pass over
// lstm computing beta + online-softmax accumulation; 4-wave LDS merge ->
// ONE partial (m, s, racc[D]) per block.
// grid = B*CPF = 1024 blocks, 256 threads (4 waves).
// ---------------------------------------------------------------------------
__global__ void k_fused(const float* __restrict__ lstm,
                        const float* __restrict__ hpart,
                        float* __restrict__ beta,
                        float* __restrict__ pm,
                        float* __restrict__ ps,
                        float* __restrict__ prb) {
    const int b    = blockIdx.x / CPF;
    const int ch   = blockIdx.x % CPF;
    const int tid  = threadIdx.x;
    const int w    = tid >> 6;
    const int lane = tid & 63;

    __shared__ alignas(16) float lracc[4][D];   // 16 KB
    __shared__ float lms[8];

    // hsum fragment for this lane's 16 columns: sum of CPH partial rows
    float4 hv[4] = {make_float4(0,0,0,0), make_float4(0,0,0,0),
                    make_float4(0,0,0,0), make_float4(0,0,0,0)};
    for (int p = 0; p < CPH; ++p) {
        const float4* pp = (const float4*)(hpart + (size_t)(b * CPH + p) * D);
#pragma unroll
        for (int k = 0; k < 4; ++k) {
            float4 v = pp[lane + 64 * k];
            hv[k].x += v.x; hv[k].y += v.y; hv[k].z += v.z; hv[k].w += v.w;
        }
    }

    float m = -INFINITY, s = 0.f;
    float4 racc[4] = {make_float4(0,0,0,0), make_float4(0,0,0,0),
                      make_float4(0,0,0,0), make_float4(0,0,0,0)};
    const int t0 = ch * RWF;
    for (int i = 0; i < RWF / 4; ++i) {
        const int t = t0 + i * 4 + w;
        const float4* lp = (const float4*)(lstm + ((size_t)b * T + t) * D);
        float4 lv[4];
#pragma unroll
        for (int k = 0; k < 4; ++k) lv[k] = lp[lane + 64 * k];

        float acc = 0.f;
#pragma unroll
        for (int k = 0; k < 4; ++k)
            acc += lv[k].x * hv[k].x + lv[k].y * hv[k].y +
                   lv[k].z * hv[k].z + lv[k].w * hv[k].w;
#pragma unroll
        for (int o = 32; o >= 1; o >>= 1) acc += __shfl_xor(acc, o, 64);
        if (lane == 0) beta[b * T + t] = acc;

        if (acc <= m) {            // wave-uniform branch (acc reduced)
            const float e = expf(acc - m);
            s += e;
#pragma unroll
            for (int k = 0; k < 4; ++k) {
                racc[k].x = fmaf(e, lv[k].x, racc[k].x);
                racc[k].y = fmaf(e, lv[k].y, racc[k].y);
                racc[k].z = fmaf(e, lv[k].z, racc[k].z);
                racc[k].w = fmaf(e, lv[k].w, racc[k].w);
            }
        } else {
            const float c2 = expf(m - acc);   // expf(-inf)=0 on first row
            s = fmaf(s, c2, 1.f);
#pragma unroll
            for (int k = 0; k < 4; ++k) {
                racc[k].x = fmaf(racc[k].x, c2, lv[k].x);
                racc[k].y = fmaf(racc[k].y, c2, lv[k].y);
                racc[k].z = fmaf(racc[k].z, c2, lv[k].z);
                racc[k].w = fmaf(racc[k].w, c2, lv[k].w);
            }
            m = acc;
        }
    }

    // 4-wave merge via LDS -> one partial per block
#pragma unroll
    for (int k = 0; k < 4; ++k)
        *(float4*)&lracc[w][(lane + 64 * k) * 4] = racc[k];
    if (lane == 0) { lms[w] = m; lms[4 + w] = s; }
    __syncthreads();

    const float mB = fmaxf(fmaxf(lms[0], lms[1]), fmaxf(lms[2], lms[3]));
    const float w0 = expf(lms[0] - mB), w1 = expf(lms[1] - mB);
    const float w2 = expf(lms[2] - mB), w3 = expf(lms[3] - mB);
    const float sB = lms[4] * w0 + lms[5] * w1 + lms[6] * w2 + lms[7] * w3;
    if (tid == 0) { pm[blockIdx.x] = mB; ps[blockIdx.x] = sB; }

    const int col = tid * 4;
    const float4 a0 = *(const float4*)&lracc[0][col];
    const float4 a1 = *(const float4*)&lracc[1][col];
    const float4 a2 = *(const float4*)&lracc[2][col];
    const float4 a3 = *(const float4*)&lracc[3][col];
    float4 rb;
    rb.x = a0.x * w0 + a1.x * w1 + a2.x * w2 + a3.x * w3;
    rb.y = a0.y * w0 + a1.y * w1 + a2.y * w2 + a3.y * w3;
    rb.z = a0.z * w0 + a1.z * w1 + a2.z * w2 + a3.z * w3;
    rb.w = a0.w * w0 + a1.w * w1 + a2.w * w2 + a3.w * w3;
    ((float4*)(prb + (size_t)blockIdx.x * D))[tid] = rb;
}

// ---------------------------------------------------------------------------
// Kernel 3: finalize.  blocks [0,B): r[b,:] combine (no atomics — block owns
// its batch).  blocks [B, B+B*ACB): alpha.
// ---------------------------------------------------------------------------
__global__ void k_final(const float* __restrict__ pm,
                        const float* __restrict__ ps,
                        const float* __restrict__ prb,
                        const float* __restrict__ beta,
                        float* __restrict__ r,
                        float* __restrict__ alpha) {
    const int tid = threadIdx.x;

    if (blockIdx.x < B) {
        const int b = blockIdx.x;
        float M = -INFINITY;
        for (int p = 0; p < CPF; ++p) M = fmaxf(M, pm[b * CPF + p]);
        float S = 0.f;
        for (int p = 0; p < CPF; ++p)
            S += expf(pm[b * CPF + p] - M) * ps[b * CPF + p];
        const float invS = 1.f / S;

        float4 acc = make_float4(0.f, 0.f, 0.f, 0.f);
        for (int p = 0; p < CPF; ++p) {
            const float wp = expf(pm[b * CPF + p] - M) * invS;
            const float4 v = ((const float4*)(prb + (size_t)(b * CPF + p) * D))[tid];
            acc.x = fmaf(wp, v.x, acc.x);
            acc.y = fmaf(wp, v.y, acc.y);
            acc.z = fmaf(wp, v.z, acc.z);
            acc.w = fmaf(wp, v.w, acc.w);
        }
        ((float4*)(r + (size_t)b * D))[tid] = acc;
    } else {
        const int idx = blockIdx.x - B;
        const int b   = idx >> 2;          // / ACB
        const int q   = idx & (ACB - 1);
        float M = -INFINITY;
        for (int p = 0; p < CPF; ++p) M = fmaxf(M, pm[b * CPF + p]);
        float S = 0.f;
        for (int p = 0; p < CPF; ++p)
            S += expf(pm[b * CPF + p] - M) * ps[b * CPF + p];
        const float invS = 1.f / S;
#pragma unroll
        for (int k = 0; k < 2; ++k) {
            const int t = q * 512 + k * 256 + tid;
            alpha[b * T + t] = expf(beta[b * T + t] - M) * invS;
        }
    }
}

// ---------------------------------------------------------------------------
extern "C" void kernel_launch(void* const* d_in, const int* in_sizes, int n_in,
                              void* d_out, int out_size, void* d_ws, size_t ws_size,
                              hipStream_t stream) {
    const float* h    = (const float*)d_in[0];   // [B,T,D]
    const float* lstm = (const float*)d_in[1];   // [B,T,D]
    const float* mask = (const float*)d_in[2];   // [B,T,H]

    float* out   = (float*)d_out;
    float* r     = out;            // [B,1,D]
    float* alpha = out + B * D;    // [B,T]

    float* hpart = (float*)d_ws;                       // B*CPH*D = 2 MB
    float* pm    = hpart + (size_t)B * CPH * D;        // B*CPF
    float* ps    = pm + B * CPF;                       // B*CPF
    float* beta  = ps + B * CPF;                       // B*T
    float* prb   = beta + (size_t)B * T;               // B*CPF*D = 4 MB

    k_hpart<<<B * CPH,     256, 0, stream>>>(h, mask, hpart);
    k_fused<<<B * CPF,     256, 0, stream>>>(lstm, hpart, beta, pm, ps, prb);
    k_final<<<B + B * ACB, 256, 0, stream>>>(pm, ps, prb, beta, r, alpha);
}